// Round 1
// 530.088 us; speedup vs baseline: 1.0157x; 1.0157x over previous
//
#include <hip/hip_runtime.h>

// DecisionGate:
//   g          = 1 / (1 + |x|^4)                      [4096, 64]  (A=1, 2B=4)
//   mask       = g >= 0.5                             [4096, 64]  (written as 0/1 float)
//   dispatched = (mask ? g : 0)[b,p] * act[b,d]       [4096, 64, 512]
//
// Output buffer layout (flat concat, float32):
//   [0 .. 262143]              g
//   [262144 .. 524287]         mask
//   [524288 .. 134742015]      dispatched
//
// Roofline: ~547 MB of HBM traffic -> write-bound, ~87 us ideal for the kernel.
// (Timed region additionally contains the harness's ~343 us output re-poison
//  fill, so total dur_us floor is ~430 us.)
//
// v2 theory: old grid (4096 x 128) == exact residency capacity -> ALL blocks
// co-resident, each streaming its own 128 KB slice -> instantaneous write set
// = entire 512 MB -> DRAM page thrash (2.8 TB/s observed). New grid: 32768
// short-lived 256-thread blocks, 16 KB contiguous writes each; 2048 resident
// -> compact ~32 MB window sliding sequentially, like the 6.3 TB/s fill.

constexpr int BATCH = 4096;
constexpr int P = 64;
constexpr int D = 512;
constexpr int PCHUNK = 8;             // gates handled per block
constexpr int NCHUNK = P / PCHUNK;    // 8 blocks per batch row

// Native vector type (works with plain stores and vector ops).
typedef float vfloat4 __attribute__((ext_vector_type(4)));

__device__ __forceinline__ float gate_val(float xv) {
    const float x2 = xv * xv;
    const float x4 = x2 * x2;         // |x/A|^(2B) with A=1, B=2
    return 1.0f / (1.0f + x4);
}

__global__ __launch_bounds__(256, 8)   // 8 wg/CU (256 thr) -> 2048 resident blocks
void decision_gate_kernel(const float* __restrict__ x,
                          const float* __restrict__ act,
                          float* __restrict__ g_out,
                          float* __restrict__ mask_out,
                          float* __restrict__ disp) {
    const int bid  = blockIdx.x;
    const int b    = bid >> 3;               // batch row
    const int p0   = (bid & (NCHUNK - 1)) * PCHUNK;
    const int t    = threadIdx.x;
    const int d4   = t & 127;                // float4 index within d (0..127)
    const int psel = t >> 7;                 // 0 or 1: which p of each pair

    // --- g / mask for this block's 8 gates (threads 0..7, one store each) ---
    if (t < PCHUNK) {
        const float g = gate_val(x[(size_t)b * P + p0 + t]);
        g_out[(size_t)b * P + p0 + t]    = g;
        mask_out[(size_t)b * P + p0 + t] = (g >= 0.5f) ? 1.0f : 0.0f;
    }

    // --- dispatch: thread owns one float4 of act[b]; 4 passes over its p's ---
    const vfloat4 a = reinterpret_cast<const vfloat4*>(act)[(size_t)b * (D / 4) + d4];

    vfloat4* out = reinterpret_cast<vfloat4*>(disp)
                 + (size_t)b * (P * D / 4)
                 + (size_t)p0 * (D / 4)
                 + d4;

    // Pass k writes local p = psel + 2k. Per wave: 64 lanes x 16 B = 1 KB
    // contiguous; per block the 4 passes cover a contiguous 16 KB region.
    #pragma unroll
    for (int k = 0; k < 4; ++k) {
        const int p = psel + 2 * k;
        const float g  = gate_val(x[(size_t)b * P + p0 + p]);  // wave-uniform load, L1 broadcast
        const float wp = (g >= 0.5f) ? g : 0.0f;
        out[(size_t)p * (D / 4)] = a * wp;
    }
}

extern "C" void kernel_launch(void* const* d_in, const int* in_sizes, int n_in,
                              void* d_out, int out_size, void* d_ws, size_t ws_size,
                              hipStream_t stream) {
    const float* x   = (const float*)d_in[0];   // [4096, 64]
    const float* act = (const float*)d_in[1];   // [4096, 512]
    // d_in[2] = batch_inds (int64) -- not needed for the dense outputs.

    float* out      = (float*)d_out;
    float* g_out    = out;                       // 4096*64
    float* mask_out = out + (size_t)BATCH * P;   // 4096*64
    float* disp     = out + (size_t)2 * BATCH * P;

    decision_gate_kernel<<<BATCH * NCHUNK, 256, 0, stream>>>(x, act, g_out, mask_out, disp);
}